// Round 16
// baseline (1907.707 us; speedup 1.0000x reference)
//
#include <hip/hip_runtime.h>
#include <math.h>

#define EPSF 1e-12f

typedef _Float16 f16x8 __attribute__((ext_vector_type(8)));
typedef _Float16 f16x2 __attribute__((ext_vector_type(2)));
typedef float f32x4 __attribute__((ext_vector_type(4)));

// sign(cs) * (|cs| + EPS)^pe with fast path for pe ~= 2.
__device__ __forceinline__ float fastpow_scs(float cs, float pe) {
    if (__builtin_fabsf(pe - 2.0f) < 1e-4f) {
        return cs * __builtin_fabsf(cs);
    }
    float m = __builtin_amdgcn_exp2f(pe * __builtin_amdgcn_logf(__builtin_fabsf(cs) + EPSF));
    return __builtin_copysignf(m, cs);
}

__device__ __forceinline__ float h2f(unsigned int bits16) {
    union { unsigned short u; _Float16 h; } z;
    z.u = (unsigned short)bits16;
    return (float)z.h;
}
__device__ __forceinline__ unsigned int pack2h(_Float16 a, _Float16 b) {
    union { _Float16 h[2]; unsigned int u; } z;
    z.h[0] = a; z.h[1] = b;
    return z.u;
}
__device__ __forceinline__ f16x2 as_h2(unsigned int u) {
    union { unsigned int u; f16x2 h; } z; z.u = u; return z.h;
}

// ss accumulate over one hi/lo word pair: shh += hi.hi, shl += hi.lo
__device__ __forceinline__ void ss_accum(unsigned int hw, unsigned int lw,
                                         float& shh, float& shl) {
#if __has_builtin(__builtin_amdgcn_fdot2)
    shh = __builtin_amdgcn_fdot2(as_h2(hw), as_h2(hw), shh, false);
    shl = __builtin_amdgcn_fdot2(as_h2(hw), as_h2(lw), shl, false);
#else
    const float h0 = h2f(hw & 0xffffu), h1 = h2f(hw >> 16);
    const float l0 = h2f(lw & 0xffffu), l1 = h2f(lw >> 16);
    shh += h0*h0 + h1*h1;
    shl += h0*l0 + h1*l1;
#endif
}

// ---------------------------------------------------------------------------
// Prep: per-cout weight norms; split-fp16 weights (hi + residual lo) in
// [tap][cout][k] layout, K-order: k -> cin = 16*(k&1) + (k>>1)  (matches the
// record word order: word w holds channels cin(2w), cin(2w+1)).
// params: [0:32)=peff1 [32:64)=peff2 [64:96)=peff3 [96]=qe1 [97]=qe2 [98]=qe3
// ---------------------------------------------------------------------------
__global__ __launch_bounds__(256) void prep_kernel(
    const float* __restrict__ w1, const float* __restrict__ p1, const float* __restrict__ q1,
    const float* __restrict__ w2, const float* __restrict__ p2, const float* __restrict__ q2,
    const float* __restrict__ w3, const float* __restrict__ p3, const float* __restrict__ q3,
    _Float16* __restrict__ wn1hi, _Float16* __restrict__ wn1lo,
    _Float16* __restrict__ wn2hi, _Float16* __restrict__ wn2lo,
    float* __restrict__ wn3, float* __restrict__ params)
{
    __shared__ float n1[32], n2[32], n3[32];
    const int tid = threadIdx.x;
    if (tid < 32) {
        float s = 0.f;
        for (int i = 0; i < 288; ++i) { float v = w1[tid*288 + i]; s += v*v; }
        n1[tid] = sqrtf(s + EPSF);
    } else if (tid < 64) {
        const int c = tid - 32; float s = 0.f;
        for (int i = 0; i < 288; ++i) { float v = w2[c*288 + i]; s += v*v; }
        n2[c] = sqrtf(s + EPSF);
    } else if (tid < 96) {
        const int c = tid - 64; float s = 0.f;
        for (int i = 0; i < 32; ++i) { float v = w3[c*32 + i]; s += v*v; }
        n3[c] = sqrtf(s + EPSF);
    }
    __syncthreads();
    // i = (t*32 + cout)*32 + k
    for (int i = tid; i < 9216; i += 256) {
        const int k    = i & 31;
        const int cout = (i >> 5) & 31;
        const int t    = i >> 10;
        const int cin  = 16*(k & 1) + (k >> 1);
        const int src  = (cout*32 + cin)*9 + t;
        const float v1 = w1[src] / n1[cout];
        const float v2 = w2[src] / n2[cout];
        const _Float16 h1v = (_Float16)v1;
        const _Float16 h2v = (_Float16)v2;
        wn1hi[i] = h1v; wn1lo[i] = (_Float16)(v1 - (float)h1v);
        wn2hi[i] = h2v; wn2lo[i] = (_Float16)(v2 - (float)h2v);
    }
    for (int i = tid; i < 1024; i += 256) {
        const int cout = i >> 5;
        wn3[i] = w3[i] / n3[cout];
    }
    if (tid < 32) {
        float a1 = p1[tid]*0.1f, a2 = p2[tid]*0.1f, a3 = p3[tid]*0.1f;
        params[tid]      = a1*a1;
        params[32 + tid] = a2*a2;
        params[64 + tid] = a3*a3;
    }
    if (tid == 0) {
        params[96] = fabsf(q1[0])*0.01f;
        params[97] = fabsf(q2[0])*0.01f;
        params[98] = fabsf(q3[0])*0.01f;
    }
}

// ---------------------------------------------------------------------------
// Geometry (r13): 32x16 output tile, halo 34x18 = 612 pixels. 512 threads =
// 8 waves; wave wv owns output rows 4wv..4wv+3 (acc[4][2]).
// Record per pixel = 128 B = 8 slots of 16 B, physical slot = logical ^ (pix&7):
// hi-plane f16x8 slots 0..3 (k-octets), lo-plane slots 4..7.
// MFMA lane map (verified r3-r15): A lane m16 -> pixel, g4 -> K-octet;
// D: cout = cf*16+m16, pixel-col = 4*g4+reg, row = 4*wv+fr.
// XCD: tileR = bx&7 -> each XCD owns one 32-row band (FETCH-optimal).
// LDS 78.9 KB -> 2 blocks/CU.
// R16: L1 blocks process 2 tiles (tileC, tileC+8); tile1's global loads are
// issued into registers BEFORE tile0's kloop (T14 async-STAGE: HBM latency
// hides under MFMA). L2 runs batches in reverse for h1 L3 residency.
// ---------------------------------------------------------------------------
#define NPIX 612

// K loop: per dj read the 6 shared halo rows ONCE (hi+lo), per di stream
// 4 weight frags, 24 MFMAs -> 72 MFMA : ~24 mem-ops per dj.
__device__ __forceinline__ void kloop4(
    const unsigned int* recs,
    const _Float16* __restrict__ wnhi, const _Float16* __restrict__ wnlo,
    f32x4 acc[4][2], int wv, int m16, int g4)
{
    #pragma unroll
    for (int dj = 0; dj < 3; ++dj) {
        f16x8 ah[6], al[6];
        #pragma unroll
        for (int rr = 0; rr < 6; ++rr) {
            const int pix = (4*wv + rr)*18 + m16 + dj;
            const int sw  = pix & 7;
            ah[rr] = *(const f16x8*)(recs + pix*32 + ((g4    ) ^ sw)*4);
            al[rr] = *(const f16x8*)(recs + pix*32 + ((4 + g4) ^ sw)*4);
        }
        #pragma unroll
        for (int di = 0; di < 3; ++di) {
            f16x8 wh[2], wl[2];
            #pragma unroll
            for (int cf = 0; cf < 2; ++cf) {
                const int o = ((di*3 + dj)*32 + cf*16 + m16)*32 + g4*8;
                wh[cf] = *(const f16x8*)(wnhi + o);
                wl[cf] = *(const f16x8*)(wnlo + o);
            }
            __builtin_amdgcn_s_setprio(1);
            #pragma unroll
            for (int fr = 0; fr < 4; ++fr)
                #pragma unroll
                for (int cf = 0; cf < 2; ++cf) {
                    acc[fr][cf] = __builtin_amdgcn_mfma_f32_16x16x32_f16(
                        ah[di + fr], wh[cf], acc[fr][cf], 0, 0, 0);
                    acc[fr][cf] = __builtin_amdgcn_mfma_f32_16x16x32_f16(
                        al[di + fr], wh[cf], acc[fr][cf], 0, 0, 0);
                    acc[fr][cf] = __builtin_amdgcn_mfma_f32_16x16x32_f16(
                        ah[di + fr], wl[cf], acc[fr][cf], 0, 0, 0);
                }
            __builtin_amdgcn_s_setprio(0);
        }
    }
}

// ---------------------------------------------------------------------------
// MERGED kernel: bx < 64  -> Layer 1, TWO tiles (tileC0, tileC0+8) with
//                            cross-tile register prefetch.
//                bx >= 64 -> residual pool+1x1 SCS (out = result).
// ---------------------------------------------------------------------------
__global__ __launch_bounds__(512, 4) void scs3x3_l1_pool(
    const float* __restrict__ x,
    const _Float16* __restrict__ wnhi, const _Float16* __restrict__ wnlo,
    const float* __restrict__ wn3, const float* __restrict__ params,
    unsigned int* __restrict__ h1, float* __restrict__ out)
{
    __shared__ alignas(16) unsigned int recs[NPIX*32];   // 78336 B
    __shared__ alignas(16) float scratch[NPIX];          //  2448 B (ss, then rden)

    const int tid = threadIdx.x;
    const int n   = blockIdx.y;

    if (blockIdx.x >= 64) {
        // ---------------- residual branch: maxabs-pool(x) + 1x1 SCS ----------
        const int pbx  = blockIdx.x - 64;           // 0..15
        const int colp = tid & 63;                  // output col pair
        const int row  = pbx*8 + (tid >> 6);        // output row 0..127

        const float* xb = x + (size_t)n*32*65536 + (size_t)(row*2)*256 + colp*4;
        float px0[32], px1[32];
        float sq0 = 0.f, sq1 = 0.f;
        #pragma unroll
        for (int cin = 0; cin < 32; ++cin) {
            const f32x4 a = *(const f32x4*)(xb + (size_t)cin*65536);        // row 2r
            const f32x4 b = *(const f32x4*)(xb + (size_t)cin*65536 + 256);  // row 2r+1
            {
                const float pos = fmaxf(fmaxf(a[0], a[1]), fmaxf(b[0], b[1]));
                const float neg = fmaxf(fmaxf(-a[0], -a[1]), fmaxf(-b[0], -b[1]));
                const float v = (pos >= neg) ? pos : -neg;
                px0[cin] = v; sq0 += v*v;
            }
            {
                const float pos = fmaxf(fmaxf(a[2], a[3]), fmaxf(b[2], b[3]));
                const float neg = fmaxf(fmaxf(-a[2], -a[3]), fmaxf(-b[2], -b[3]));
                const float v = (pos >= neg) ? pos : -neg;
                px1[cin] = v; sq1 += v*v;
            }
        }
        const float qe  = params[98];
        const float rd0 = 1.f / (sqrtf(sq0 + EPSF) + qe);
        const float rd1 = 1.f / (sqrtf(sq1 + EPSF) + qe);

        #pragma unroll 4
        for (int cout = 0; cout < 32; ++cout) {
            const float* wr = wn3 + cout*32;   // wave-uniform -> s_load
            float a0 = 0.f, a1 = 0.f;
            #pragma unroll
            for (int cin = 0; cin < 32; ++cin) {
                a0 = fmaf(px0[cin], wr[cin], a0);
                a1 = fmaf(px1[cin], wr[cin], a1);
            }
            const float pe = params[64 + cout];
            const float r0 = fastpow_scs(a0*rd0, pe);
            const float r1 = fastpow_scs(a1*rd1, pe);
            float* po = out + (((size_t)n*32 + cout)*128 + row)*128 + colp*2;
            *(float2*)po = make_float2(r0, r1);   // overwrite; L2 adds main path
        }
        return;
    }

    // ---------------- Layer 1: two tiles with cross-tile prefetch ------------
    const int tileR = blockIdx.x & 7;    // XCD-aligned 32-row band
    const int tC0   = blockIdx.x >> 3;   // 0..7; tiles tC0 and tC0+8
    const int lane  = tid & 63;
    const int wv    = tid >> 6;
    const int m16   = lane & 15;
    const int g4    = lane >> 4;

    const float* xin = x + (size_t)n * 32 * 65536;

    float vx[32];
    // prefetch pixel tid of tile 0
    {
        const int p = tid;
        const int ro = p / 18, co = p - ro*18;
        const int gr = tileR*32 + ro - 1;
        const int gc = tC0*16 + co - 1;
        const bool ok = ((unsigned)gr < 256u) && ((unsigned)gc < 256u);
        const int base = gr*256 + gc;
        #pragma unroll
        for (int k = 0; k < 32; ++k) {
            const int cin = 16*(k & 1) + (k >> 1);
            vx[k] = ok ? xin[(size_t)cin*65536 + base] : 0.f;
        }
    }

    #pragma unroll 1
    for (int t = 0; t < 2; ++t) {
        const int tileC = tC0 + 8*t;

        // ---- write stage: pixel tid from prefetched regs (same op order)
        {
            const int p = tid;
            const int sw = p & 7;
            float s = 0.f;
            #pragma unroll
            for (int q = 0; q < 4; ++q) {
                f16x8 hi, lo;
                #pragma unroll
                for (int j = 0; j < 8; ++j) {
                    const float v = vx[8*q + j];
                    s += v*v;
                    hi[j] = (_Float16)v;
                    lo[j] = (_Float16)(v - (float)hi[j]);
                }
                *(f16x8*)(recs + p*32 + ((q    ) ^ sw)*4) = hi;
                *(f16x8*)(recs + p*32 + ((4 + q) ^ sw)*4) = lo;
            }
            scratch[p] = s;
        }
        // ---- leftover pixels 512..611: inline gather (original path)
        if (tid < 100) {
            const int p = 512 + tid;
            const int ro = p / 18, co = p - ro*18;
            const int gr = tileR*32 + ro - 1;
            const int gc = tileC*16 + co - 1;
            const bool ok = ((unsigned)gr < 256u) && ((unsigned)gc < 256u);
            const int base = gr*256 + gc;
            const int sw = p & 7;
            float s = 0.f;
            #pragma unroll
            for (int q = 0; q < 4; ++q) {
                f16x8 hi, lo;
                #pragma unroll
                for (int j = 0; j < 8; ++j) {
                    const int k   = 8*q + j;
                    const int cin = 16*(k & 1) + (k >> 1);
                    const float v = ok ? xin[(size_t)cin*65536 + base] : 0.f;
                    s += v*v;
                    hi[j] = (_Float16)v;
                    lo[j] = (_Float16)(v - (float)hi[j]);
                }
                *(f16x8*)(recs + p*32 + ((q    ) ^ sw)*4) = hi;
                *(f16x8*)(recs + p*32 + ((4 + q) ^ sw)*4) = lo;
            }
            scratch[p] = s;
        }
        __syncthreads();

        // ---- window sums -> rden
        float rd;
        {
            const int r = tid >> 4, c = tid & 15;
            float sq = 0.f;
            #pragma unroll
            for (int di = 0; di < 3; ++di)
                #pragma unroll
                for (int dc = 0; dc < 3; ++dc)
                    sq += scratch[(r + di)*18 + c + dc];
            rd = 1.f / (sqrtf(sq + EPSF) + params[96]);
        }
        __syncthreads();
        scratch[tid] = rd;
        __syncthreads();

        // ---- prefetch NEXT tile before the kloop: HBM latency hides
        // under ~16K cycles of MFMA below. sched_barrier pins issue order.
        if (t == 0) {
            const int p = tid;
            const int ro = p / 18, co = p - ro*18;
            const int gr = tileR*32 + ro - 1;
            const int gc = (tC0 + 8)*16 + co - 1;
            const bool ok = ((unsigned)gr < 256u) && ((unsigned)gc < 256u);
            const int base = gr*256 + gc;
            #pragma unroll
            for (int k = 0; k < 32; ++k) {
                const int cin = 16*(k & 1) + (k >> 1);
                vx[k] = ok ? xin[(size_t)cin*65536 + base] : 0.f;
            }
            __builtin_amdgcn_sched_barrier(0);
        }

        // ---- K loop
        f32x4 acc[4][2];
        #pragma unroll
        for (int fr = 0; fr < 4; ++fr)
            #pragma unroll
            for (int cf = 0; cf < 2; ++cf)
                acc[fr][cf] = (f32x4){0.f, 0.f, 0.f, 0.f};
        kloop4(recs, wnhi, wnlo, acc, wv, m16, g4);

        // ---- epilogue: pow + split; write plane words m16 (hi), 16+m16 (lo)
        {
            unsigned int* hq = h1 + (size_t)n * 65536 * 32;
            const float pe0 = params[m16];
            const float pe1 = params[16 + m16];
            #pragma unroll
            for (int fr = 0; fr < 4; ++fr) {
                const int r_loc = 4*wv + fr;
                const f32x4 rv = *(const f32x4*)(scratch + r_loc*16 + 4*g4);
                const int gr = tileR*32 + r_loc;
                #pragma unroll
                for (int reg = 0; reg < 4; ++reg) {
                    const int gc = tileC*16 + 4*g4 + reg;
                    const float r0 = fastpow_scs(acc[fr][0][reg] * rv[reg], pe0);
                    const float r1 = fastpow_scs(acc[fr][1][reg] * rv[reg], pe1);
                    const _Float16 h0 = (_Float16)r0, h1v = (_Float16)r1;
                    const _Float16 l0 = (_Float16)(r0 - (float)h0);
                    const _Float16 l1 = (_Float16)(r1 - (float)h1v);
                    unsigned int* rec = hq + (size_t)(gr*256 + gc)*32;
                    rec[m16]      = pack2h(h0, h1v);   // hi-plane word
                    rec[16 + m16] = pack2h(l0, l1);    // lo-plane word
                }
            }
        }

        if (t == 0) __syncthreads();   // all recs/scratch reads done before reuse
    }
}

// ---------------------------------------------------------------------------
// Layer 2 + maxabs pool: h1 f16-pair records -> out += pooled (fp32 NCHW 128^2).
// Stage: 4 lanes per record (copy + inline ss via fdot2 + shfl combine).
// R16: batches processed in REVERSE so the h1 batches most recently written
// by L1 are still L3-resident when L2 reads them.
// ---------------------------------------------------------------------------
__global__ __launch_bounds__(512, 4) void scs3x3_l2(
    const unsigned int* __restrict__ h1,
    const _Float16* __restrict__ wnhi, const _Float16* __restrict__ wnlo,
    const float* __restrict__ peff, const float* __restrict__ qeffp,
    float* __restrict__ out)
{
    __shared__ alignas(16) unsigned int recs[NPIX*32];   // 78336 B
    __shared__ alignas(16) float scratch[NPIX];          //  2448 B

    const int tid   = threadIdx.x;
    const int tileR = blockIdx.x & 7;
    const int tileC = blockIdx.x >> 3;
    const int n     = 31 - blockIdx.y;   // reverse batch order (L3 residency)
    const int lane  = tid & 63;
    const int wv    = tid >> 6;
    const int m16   = lane & 15;
    const int g4    = lane >> 4;

    const unsigned int* hb = h1 + (size_t)n * 65536 * 32;

    // ---- stage: copy + inline ss (4 lanes cover one 128B record)
    for (int i = tid; i < NPIX*4; i += 512) {
        const int p = i >> 2, q = i & 3;
        const int ro = p / 18, co = p - ro*18;
        const int gr = tileR*32 + ro - 1;
        const int gc = tileC*16 + co - 1;
        uint4 h = make_uint4(0u,0u,0u,0u), l = make_uint4(0u,0u,0u,0u);
        if (((unsigned)gr < 256u) && ((unsigned)gc < 256u)) {
            const unsigned int* rec = hb + (size_t)(gr*256 + gc)*32;
            h = *(const uint4*)(rec + q*4);          // hi slot q
            l = *(const uint4*)(rec + 16 + q*4);     // lo slot q
        }
        float shh = 0.f, shl = 0.f;
        ss_accum(h.x, l.x, shh, shl);
        ss_accum(h.y, l.y, shh, shl);
        ss_accum(h.z, l.z, shh, shl);
        ss_accum(h.w, l.w, shh, shl);
        float s = shh + 2.f*shl;                     // drop lo^2 (~2^-22 rel)
        s += __shfl_xor(s, 1);
        s += __shfl_xor(s, 2);
        const int sw = p & 7;
        *(uint4*)(recs + p*32 + ((q    ) ^ sw)*4) = h;
        *(uint4*)(recs + p*32 + ((4 + q) ^ sw)*4) = l;
        if (q == 0) scratch[p] = s;
    }
    __syncthreads();

    float rd;
    {
        const int r = tid >> 4, c = tid & 15;
        float sq = 0.f;
        #pragma unroll
        for (int di = 0; di < 3; ++di)
            #pragma unroll
            for (int dc = 0; dc < 3; ++dc)
                sq += scratch[(r + di)*18 + c + dc];
        rd = 1.f / (sqrtf(sq + EPSF) + qeffp[0]);
    }
    __syncthreads();
    scratch[tid] = rd;
    __syncthreads();

    // ---- K loop
    f32x4 acc[4][2];
    #pragma unroll
    for (int fr = 0; fr < 4; ++fr)
        #pragma unroll
        for (int cf = 0; cf < 2; ++cf)
            acc[fr][cf] = (f32x4){0.f, 0.f, 0.f, 0.f};
    kloop4(recs, wnhi, wnlo, acc, wv, m16, g4);

    // ---- epilogue: 2x2 maxabs pool, pow after pool, out += (residual there)
    const float pe0 = peff[m16];
    const float pe1 = peff[16 + m16];
    #pragma unroll
    for (int rp = 0; rp < 2; ++rp) {
        const int r0 = 4*wv + 2*rp;
        const f32x4 rv0 = *(const f32x4*)(scratch + r0*16 + 4*g4);
        const f32x4 rv1 = *(const f32x4*)(scratch + (r0 + 1)*16 + 4*g4);
        const int orow = tileR*16 + 2*wv + rp;
        const int ocol = tileC*8 + 2*g4;
        #pragma unroll
        for (int cf = 0; cf < 2; ++cf) {
            const int cout = cf*16 + m16;
            const float pe = cf ? pe1 : pe0;
            float o2[2];
            #pragma unroll
            for (int cp = 0; cp < 2; ++cp) {
                const float a0 = acc[2*rp    ][cf][2*cp    ] * rv0[2*cp    ];
                const float a1 = acc[2*rp    ][cf][2*cp + 1] * rv0[2*cp + 1];
                const float b0 = acc[2*rp + 1][cf][2*cp    ] * rv1[2*cp    ];
                const float b1 = acc[2*rp + 1][cf][2*cp + 1] * rv1[2*cp + 1];
                const float pos = fmaxf(fmaxf(a0, a1), fmaxf(b0, b1));
                const float neg = fmaxf(fmaxf(-a0, -a1), fmaxf(-b0, -b1));
                const float pooled = (pos >= neg) ? pos : -neg;
                o2[cp] = fastpow_scs(pooled, pe);
            }
            float2* po = (float2*)(out + (((size_t)n*32 + cout)*128 + orow)*128 + ocol);
            const float2 cur = *po;
            *po = make_float2(cur.x + o2[0], cur.y + o2[1]);
        }
    }
}

// ---------------------------------------------------------------------------
extern "C" void kernel_launch(void* const* d_in, const int* in_sizes, int n_in,
                              void* d_out, int out_size, void* d_ws, size_t ws_size,
                              hipStream_t stream)
{
    (void)in_sizes; (void)n_in; (void)out_size;
    const float* x  = (const float*)d_in[0];
    const float* w1 = (const float*)d_in[1];
    const float* p1 = (const float*)d_in[2];
    const float* q1 = (const float*)d_in[3];
    const float* w2 = (const float*)d_in[4];
    const float* p2 = (const float*)d_in[5];
    const float* q2 = (const float*)d_in[6];
    const float* w3 = (const float*)d_in[7];
    const float* p3 = (const float*)d_in[8];
    const float* q3 = (const float*)d_in[9];

    char* wsb = (char*)d_ws;
    _Float16* wn1hi = (_Float16*)(wsb);          // 9216 f16 = 18432 B
    _Float16* wn1lo = (_Float16*)(wsb + 18432);
    _Float16* wn2hi = (_Float16*)(wsb + 36864);
    _Float16* wn2lo = (_Float16*)(wsb + 55296);
    float*    wn3   = (float*)(wsb + 73728);     // 1024 f32 = 4096 B
    float*    params= (float*)(wsb + 77824);     //  128 f32 =  512 B
    unsigned int* h1= (unsigned int*)(wsb + 78336);  // 32*65536*32 u32 = 268435456 B

    const size_t need = 78336 + (size_t)32*65536*32*4;
    if (ws_size < need) return;  // fail visibly rather than corrupt memory

    float* out = (float*)d_out;

    prep_kernel<<<1, 256, 0, stream>>>(w1,p1,q1, w2,p2,q2, w3,p3,q3,
                                       wn1hi, wn1lo, wn2hi, wn2lo, wn3, params);

    // merged: L1 two-tiles-with-prefetch (bx<64) + residual pool (bx in [64,80))
    scs3x3_l1_pool<<<dim3(80, 32), 512, 0, stream>>>(
        x, wn1hi, wn1lo, wn3, params, h1, out);

    // layer 2 + maxabs pool (reverse batch order): h1 -> out += pooled
    scs3x3_l2<<<dim3(128, 32), 512, 0, stream>>>(
        h1, wn2hi, wn2lo, params+32, params+97, out);
}

// Round 17
// 396.829 us; speedup vs baseline: 4.8074x; 4.8074x over previous
//
#include <hip/hip_runtime.h>
#include <math.h>

#define EPSF 1e-12f

typedef _Float16 f16x8 __attribute__((ext_vector_type(8)));
typedef _Float16 f16x2 __attribute__((ext_vector_type(2)));
typedef float f32x4 __attribute__((ext_vector_type(4)));

// sign(cs) * (|cs| + EPS)^pe with fast path for pe ~= 2.
__device__ __forceinline__ float fastpow_scs(float cs, float pe) {
    if (__builtin_fabsf(pe - 2.0f) < 1e-4f) {
        return cs * __builtin_fabsf(cs);
    }
    float m = __builtin_amdgcn_exp2f(pe * __builtin_amdgcn_logf(__builtin_fabsf(cs) + EPSF));
    return __builtin_copysignf(m, cs);
}

__device__ __forceinline__ float h2f(unsigned int bits16) {
    union { unsigned short u; _Float16 h; } z;
    z.u = (unsigned short)bits16;
    return (float)z.h;
}
__device__ __forceinline__ unsigned int pack2h(_Float16 a, _Float16 b) {
    union { _Float16 h[2]; unsigned int u; } z;
    z.h[0] = a; z.h[1] = b;
    return z.u;
}
__device__ __forceinline__ f16x2 as_h2(unsigned int u) {
    union { unsigned int u; f16x2 h; } z; z.u = u; return z.h;
}

// ss accumulate over one hi/lo word pair: shh += hi.hi, shl += hi.lo
__device__ __forceinline__ void ss_accum(unsigned int hw, unsigned int lw,
                                         float& shh, float& shl) {
#if __has_builtin(__builtin_amdgcn_fdot2)
    shh = __builtin_amdgcn_fdot2(as_h2(hw), as_h2(hw), shh, false);
    shl = __builtin_amdgcn_fdot2(as_h2(hw), as_h2(lw), shl, false);
#else
    const float h0 = h2f(hw & 0xffffu), h1 = h2f(hw >> 16);
    const float l0 = h2f(lw & 0xffffu), l1 = h2f(lw >> 16);
    shh += h0*h0 + h1*h1;
    shl += h0*l0 + h1*l1;
#endif
}

// ---------------------------------------------------------------------------
// Prep: per-cout weight norms; split-fp16 weights (hi + residual lo) in
// [tap][cout][k] layout, K-order: k -> cin = 16*(k&1) + (k>>1)  (matches the
// record word order: word w holds channels cin(2w), cin(2w+1)).
// params: [0:32)=peff1 [32:64)=peff2 [64:96)=peff3 [96]=qe1 [97]=qe2 [98]=qe3
// ---------------------------------------------------------------------------
__global__ __launch_bounds__(256) void prep_kernel(
    const float* __restrict__ w1, const float* __restrict__ p1, const float* __restrict__ q1,
    const float* __restrict__ w2, const float* __restrict__ p2, const float* __restrict__ q2,
    const float* __restrict__ w3, const float* __restrict__ p3, const float* __restrict__ q3,
    _Float16* __restrict__ wn1hi, _Float16* __restrict__ wn1lo,
    _Float16* __restrict__ wn2hi, _Float16* __restrict__ wn2lo,
    float* __restrict__ wn3, float* __restrict__ params)
{
    __shared__ float n1[32], n2[32], n3[32];
    const int tid = threadIdx.x;
    if (tid < 32) {
        float s = 0.f;
        for (int i = 0; i < 288; ++i) { float v = w1[tid*288 + i]; s += v*v; }
        n1[tid] = sqrtf(s + EPSF);
    } else if (tid < 64) {
        const int c = tid - 32; float s = 0.f;
        for (int i = 0; i < 288; ++i) { float v = w2[c*288 + i]; s += v*v; }
        n2[c] = sqrtf(s + EPSF);
    } else if (tid < 96) {
        const int c = tid - 64; float s = 0.f;
        for (int i = 0; i < 32; ++i) { float v = w3[c*32 + i]; s += v*v; }
        n3[c] = sqrtf(s + EPSF);
    }
    __syncthreads();
    // i = (t*32 + cout)*32 + k
    for (int i = tid; i < 9216; i += 256) {
        const int k    = i & 31;
        const int cout = (i >> 5) & 31;
        const int t    = i >> 10;
        const int cin  = 16*(k & 1) + (k >> 1);
        const int src  = (cout*32 + cin)*9 + t;
        const float v1 = w1[src] / n1[cout];
        const float v2 = w2[src] / n2[cout];
        const _Float16 h1v = (_Float16)v1;
        const _Float16 h2v = (_Float16)v2;
        wn1hi[i] = h1v; wn1lo[i] = (_Float16)(v1 - (float)h1v);
        wn2hi[i] = h2v; wn2lo[i] = (_Float16)(v2 - (float)h2v);
    }
    for (int i = tid; i < 1024; i += 256) {
        const int cout = i >> 5;
        wn3[i] = w3[i] / n3[cout];
    }
    if (tid < 32) {
        float a1 = p1[tid]*0.1f, a2 = p2[tid]*0.1f, a3 = p3[tid]*0.1f;
        params[tid]      = a1*a1;
        params[32 + tid] = a2*a2;
        params[64 + tid] = a3*a3;
    }
    if (tid == 0) {
        params[96] = fabsf(q1[0])*0.01f;
        params[97] = fabsf(q2[0])*0.01f;
        params[98] = fabsf(q3[0])*0.01f;
    }
}

// ---------------------------------------------------------------------------
// Geometry (r13, best): 32x16 output tile, halo 34x18 = 612 pixels.
// 512 threads = 8 waves; wave wv owns output rows 4wv..4wv+3 (acc[4][2]).
// Record per pixel = 128 B = 8 slots of 16 B, physical slot = logical ^ (pix&7):
// hi-plane f16x8 slots 0..3 (k-octets), lo-plane slots 4..7.
// MFMA lane map (verified r3-r16): A lane m16 -> pixel, g4 -> K-octet;
// D: cout = cf*16+m16, pixel-col = 4*g4+reg, row = 4*wv+fr.
// XCD: tileR = bx&7 -> each XCD owns one 32-row band (FETCH-optimal, 139MB).
// LDS 78.9 KB -> 2 blocks/CU.
// R17 = r13 + L2 reverse-batch (h1 L3 residency). No register prefetch (r16
// lesson: 32 regs held across the kloop spill -> 6.5 GB scratch traffic).
// ---------------------------------------------------------------------------
#define NPIX 612

// K loop: per dj read the 6 shared halo rows ONCE (hi+lo), per di stream
// 4 weight frags, 24 MFMAs -> 72 MFMA : ~24 mem-ops per dj.
__device__ __forceinline__ void kloop4(
    const unsigned int* recs,
    const _Float16* __restrict__ wnhi, const _Float16* __restrict__ wnlo,
    f32x4 acc[4][2], int wv, int m16, int g4)
{
    #pragma unroll
    for (int dj = 0; dj < 3; ++dj) {
        f16x8 ah[6], al[6];
        #pragma unroll
        for (int rr = 0; rr < 6; ++rr) {
            const int pix = (4*wv + rr)*18 + m16 + dj;
            const int sw  = pix & 7;
            ah[rr] = *(const f16x8*)(recs + pix*32 + ((g4    ) ^ sw)*4);
            al[rr] = *(const f16x8*)(recs + pix*32 + ((4 + g4) ^ sw)*4);
        }
        #pragma unroll
        for (int di = 0; di < 3; ++di) {
            f16x8 wh[2], wl[2];
            #pragma unroll
            for (int cf = 0; cf < 2; ++cf) {
                const int o = ((di*3 + dj)*32 + cf*16 + m16)*32 + g4*8;
                wh[cf] = *(const f16x8*)(wnhi + o);
                wl[cf] = *(const f16x8*)(wnlo + o);
            }
            #pragma unroll
            for (int fr = 0; fr < 4; ++fr)
                #pragma unroll
                for (int cf = 0; cf < 2; ++cf) {
                    acc[fr][cf] = __builtin_amdgcn_mfma_f32_16x16x32_f16(
                        ah[di + fr], wh[cf], acc[fr][cf], 0, 0, 0);
                    acc[fr][cf] = __builtin_amdgcn_mfma_f32_16x16x32_f16(
                        al[di + fr], wh[cf], acc[fr][cf], 0, 0, 0);
                    acc[fr][cf] = __builtin_amdgcn_mfma_f32_16x16x32_f16(
                        ah[di + fr], wl[cf], acc[fr][cf], 0, 0, 0);
                }
        }
    }
}

// ---------------------------------------------------------------------------
// MERGED kernel: bx < 128  -> Layer 1 (x -> h1 records).
//                bx >= 128 -> residual pool+1x1 SCS (out = result), independent
// streaming work interleaved with L1 blocks to fill L1's phase-stall bubbles.
// ---------------------------------------------------------------------------
__global__ __launch_bounds__(512, 4) void scs3x3_l1_pool(
    const float* __restrict__ x,
    const _Float16* __restrict__ wnhi, const _Float16* __restrict__ wnlo,
    const float* __restrict__ wn3, const float* __restrict__ params,
    unsigned int* __restrict__ h1, float* __restrict__ out)
{
    __shared__ alignas(16) unsigned int recs[NPIX*32];   // 78336 B
    __shared__ alignas(16) float scratch[NPIX];          //  2448 B (ss, then rden)

    const int tid = threadIdx.x;
    const int n   = blockIdx.y;

    if (blockIdx.x >= 128) {
        // ---------------- residual branch: maxabs-pool(x) + 1x1 SCS ----------
        const int pbx  = blockIdx.x - 128;          // 0..15
        const int colp = tid & 63;                  // output col pair
        const int row  = pbx*8 + (tid >> 6);        // output row 0..127

        const float* xb = x + (size_t)n*32*65536 + (size_t)(row*2)*256 + colp*4;
        float px0[32], px1[32];
        float sq0 = 0.f, sq1 = 0.f;
        #pragma unroll
        for (int cin = 0; cin < 32; ++cin) {
            const f32x4 a = *(const f32x4*)(xb + (size_t)cin*65536);        // row 2r
            const f32x4 b = *(const f32x4*)(xb + (size_t)cin*65536 + 256);  // row 2r+1
            {
                const float pos = fmaxf(fmaxf(a[0], a[1]), fmaxf(b[0], b[1]));
                const float neg = fmaxf(fmaxf(-a[0], -a[1]), fmaxf(-b[0], -b[1]));
                const float v = (pos >= neg) ? pos : -neg;
                px0[cin] = v; sq0 += v*v;
            }
            {
                const float pos = fmaxf(fmaxf(a[2], a[3]), fmaxf(b[2], b[3]));
                const float neg = fmaxf(fmaxf(-a[2], -a[3]), fmaxf(-b[2], -b[3]));
                const float v = (pos >= neg) ? pos : -neg;
                px1[cin] = v; sq1 += v*v;
            }
        }
        const float qe  = params[98];
        const float rd0 = 1.f / (sqrtf(sq0 + EPSF) + qe);
        const float rd1 = 1.f / (sqrtf(sq1 + EPSF) + qe);

        #pragma unroll 4
        for (int cout = 0; cout < 32; ++cout) {
            const float* wr = wn3 + cout*32;   // wave-uniform -> s_load
            float a0 = 0.f, a1 = 0.f;
            #pragma unroll
            for (int cin = 0; cin < 32; ++cin) {
                a0 = fmaf(px0[cin], wr[cin], a0);
                a1 = fmaf(px1[cin], wr[cin], a1);
            }
            const float pe = params[64 + cout];
            const float r0 = fastpow_scs(a0*rd0, pe);
            const float r1 = fastpow_scs(a1*rd1, pe);
            float* po = out + (((size_t)n*32 + cout)*128 + row)*128 + colp*2;
            *(float2*)po = make_float2(r0, r1);   // overwrite; L2 adds main path
        }
        return;
    }

    // ---------------- Layer 1 (r13-identical) --------------------------------
    const int tileR = blockIdx.x & 7;    // XCD-aligned 32-row band
    const int tileC = blockIdx.x >> 3;   // 0..15
    const int lane  = tid & 63;
    const int wv    = tid >> 6;
    const int m16   = lane & 15;
    const int g4    = lane >> 4;

    const float* xin = x + (size_t)n * 32 * 65536;

    // ---- stage: thread-per-pixel gather, split fp32 -> hi/lo plane records
    for (int p = tid; p < NPIX; p += 512) {
        const int ro = p / 18, co = p - ro*18;
        const int gr = tileR*32 + ro - 1;
        const int gc = tileC*16 + co - 1;
        const bool ok = ((unsigned)gr < 256u) && ((unsigned)gc < 256u);
        const int base = gr*256 + gc;
        const int sw = p & 7;
        float s = 0.f;
        #pragma unroll
        for (int q = 0; q < 4; ++q) {
            f16x8 hi, lo;
            #pragma unroll
            for (int j = 0; j < 8; ++j) {
                const int k   = 8*q + j;
                const int cin = 16*(k & 1) + (k >> 1);
                const float v = ok ? xin[(size_t)cin*65536 + base] : 0.f;
                s += v*v;
                hi[j] = (_Float16)v;
                lo[j] = (_Float16)(v - (float)hi[j]);
            }
            *(f16x8*)(recs + p*32 + ((q    ) ^ sw)*4) = hi;
            *(f16x8*)(recs + p*32 + ((4 + q) ^ sw)*4) = lo;
        }
        scratch[p] = s;
    }
    __syncthreads();

    // ---- window sums -> rden (reuse scratch after all reads complete)
    float rd;
    {
        const int r = tid >> 4, c = tid & 15;
        float sq = 0.f;
        #pragma unroll
        for (int di = 0; di < 3; ++di)
            #pragma unroll
            for (int dc = 0; dc < 3; ++dc)
                sq += scratch[(r + di)*18 + c + dc];
        rd = 1.f / (sqrtf(sq + EPSF) + params[96]);
    }
    __syncthreads();
    scratch[tid] = rd;
    __syncthreads();

    // ---- K loop
    f32x4 acc[4][2];
    #pragma unroll
    for (int fr = 0; fr < 4; ++fr)
        #pragma unroll
        for (int cf = 0; cf < 2; ++cf)
            acc[fr][cf] = (f32x4){0.f, 0.f, 0.f, 0.f};
    kloop4(recs, wnhi, wnlo, acc, wv, m16, g4);

    // ---- epilogue: pow + split; write plane words m16 (hi), 16+m16 (lo)
    unsigned int* hq = h1 + (size_t)n * 65536 * 32;
    const float pe0 = params[m16];
    const float pe1 = params[16 + m16];
    #pragma unroll
    for (int fr = 0; fr < 4; ++fr) {
        const int r_loc = 4*wv + fr;
        const f32x4 rv = *(const f32x4*)(scratch + r_loc*16 + 4*g4);
        const int gr = tileR*32 + r_loc;
        #pragma unroll
        for (int reg = 0; reg < 4; ++reg) {
            const int gc = tileC*16 + 4*g4 + reg;
            const float r0 = fastpow_scs(acc[fr][0][reg] * rv[reg], pe0);
            const float r1 = fastpow_scs(acc[fr][1][reg] * rv[reg], pe1);
            const _Float16 h0 = (_Float16)r0, h1v = (_Float16)r1;
            const _Float16 l0 = (_Float16)(r0 - (float)h0);
            const _Float16 l1 = (_Float16)(r1 - (float)h1v);
            unsigned int* rec = hq + (size_t)(gr*256 + gc)*32;
            rec[m16]      = pack2h(h0, h1v);   // hi-plane word m16 (k=2m16,2m16+1)
            rec[16 + m16] = pack2h(l0, l1);    // lo-plane word
        }
    }
}

// ---------------------------------------------------------------------------
// Layer 2 + maxabs pool: h1 f16-pair records -> out += pooled (fp32 NCHW 128^2).
// Stage: 4 lanes per record (copy + inline ss via fdot2 + shfl combine).
// R17: batches processed in REVERSE (n = 31 - by) so the h1 batches most
// recently written by L1 are still L3-resident when L2 reads them.
// ---------------------------------------------------------------------------
__global__ __launch_bounds__(512, 4) void scs3x3_l2(
    const unsigned int* __restrict__ h1,
    const _Float16* __restrict__ wnhi, const _Float16* __restrict__ wnlo,
    const float* __restrict__ peff, const float* __restrict__ qeffp,
    float* __restrict__ out)
{
    __shared__ alignas(16) unsigned int recs[NPIX*32];   // 78336 B
    __shared__ alignas(16) float scratch[NPIX];          //  2448 B

    const int tid   = threadIdx.x;
    const int tileR = blockIdx.x & 7;
    const int tileC = blockIdx.x >> 3;
    const int n     = 31 - blockIdx.y;   // reverse batch order (L3 residency)
    const int lane  = tid & 63;
    const int wv    = tid >> 6;
    const int m16   = lane & 15;
    const int g4    = lane >> 4;

    const unsigned int* hb = h1 + (size_t)n * 65536 * 32;

    // ---- stage: copy + inline ss (4 lanes cover one 128B record)
    for (int i = tid; i < NPIX*4; i += 512) {
        const int p = i >> 2, q = i & 3;
        const int ro = p / 18, co = p - ro*18;
        const int gr = tileR*32 + ro - 1;
        const int gc = tileC*16 + co - 1;
        uint4 h = make_uint4(0u,0u,0u,0u), l = make_uint4(0u,0u,0u,0u);
        if (((unsigned)gr < 256u) && ((unsigned)gc < 256u)) {
            const unsigned int* rec = hb + (size_t)(gr*256 + gc)*32;
            h = *(const uint4*)(rec + q*4);          // hi slot q
            l = *(const uint4*)(rec + 16 + q*4);     // lo slot q
        }
        float shh = 0.f, shl = 0.f;
        ss_accum(h.x, l.x, shh, shl);
        ss_accum(h.y, l.y, shh, shl);
        ss_accum(h.z, l.z, shh, shl);
        ss_accum(h.w, l.w, shh, shl);
        float s = shh + 2.f*shl;                     // drop lo^2 (~2^-22 rel)
        s += __shfl_xor(s, 1);
        s += __shfl_xor(s, 2);
        const int sw = p & 7;
        *(uint4*)(recs + p*32 + ((q    ) ^ sw)*4) = h;
        *(uint4*)(recs + p*32 + ((4 + q) ^ sw)*4) = l;
        if (q == 0) scratch[p] = s;
    }
    __syncthreads();

    float rd;
    {
        const int r = tid >> 4, c = tid & 15;
        float sq = 0.f;
        #pragma unroll
        for (int di = 0; di < 3; ++di)
            #pragma unroll
            for (int dc = 0; dc < 3; ++dc)
                sq += scratch[(r + di)*18 + c + dc];
        rd = 1.f / (sqrtf(sq + EPSF) + qeffp[0]);
    }
    __syncthreads();
    scratch[tid] = rd;
    __syncthreads();

    // ---- K loop
    f32x4 acc[4][2];
    #pragma unroll
    for (int fr = 0; fr < 4; ++fr)
        #pragma unroll
        for (int cf = 0; cf < 2; ++cf)
            acc[fr][cf] = (f32x4){0.f, 0.f, 0.f, 0.f};
    kloop4(recs, wnhi, wnlo, acc, wv, m16, g4);

    // ---- epilogue: 2x2 maxabs pool, pow after pool, out += (residual there)
    const float pe0 = peff[m16];
    const float pe1 = peff[16 + m16];
    #pragma unroll
    for (int rp = 0; rp < 2; ++rp) {
        const int r0 = 4*wv + 2*rp;
        const f32x4 rv0 = *(const f32x4*)(scratch + r0*16 + 4*g4);
        const f32x4 rv1 = *(const f32x4*)(scratch + (r0 + 1)*16 + 4*g4);
        const int orow = tileR*16 + 2*wv + rp;
        const int ocol = tileC*8 + 2*g4;
        #pragma unroll
        for (int cf = 0; cf < 2; ++cf) {
            const int cout = cf*16 + m16;
            const float pe = cf ? pe1 : pe0;
            float o2[2];
            #pragma unroll
            for (int cp = 0; cp < 2; ++cp) {
                const float a0 = acc[2*rp    ][cf][2*cp    ] * rv0[2*cp    ];
                const float a1 = acc[2*rp    ][cf][2*cp + 1] * rv0[2*cp + 1];
                const float b0 = acc[2*rp + 1][cf][2*cp    ] * rv1[2*cp    ];
                const float b1 = acc[2*rp + 1][cf][2*cp + 1] * rv1[2*cp + 1];
                const float pos = fmaxf(fmaxf(a0, a1), fmaxf(b0, b1));
                const float neg = fmaxf(fmaxf(-a0, -a1), fmaxf(-b0, -b1));
                const float pooled = (pos >= neg) ? pos : -neg;
                o2[cp] = fastpow_scs(pooled, pe);
            }
            float2* po = (float2*)(out + (((size_t)n*32 + cout)*128 + orow)*128 + ocol);
            const float2 cur = *po;
            *po = make_float2(cur.x + o2[0], cur.y + o2[1]);
        }
    }
}

// ---------------------------------------------------------------------------
extern "C" void kernel_launch(void* const* d_in, const int* in_sizes, int n_in,
                              void* d_out, int out_size, void* d_ws, size_t ws_size,
                              hipStream_t stream)
{
    (void)in_sizes; (void)n_in; (void)out_size;
    const float* x  = (const float*)d_in[0];
    const float* w1 = (const float*)d_in[1];
    const float* p1 = (const float*)d_in[2];
    const float* q1 = (const float*)d_in[3];
    const float* w2 = (const float*)d_in[4];
    const float* p2 = (const float*)d_in[5];
    const float* q2 = (const float*)d_in[6];
    const float* w3 = (const float*)d_in[7];
    const float* p3 = (const float*)d_in[8];
    const float* q3 = (const float*)d_in[9];

    char* wsb = (char*)d_ws;
    _Float16* wn1hi = (_Float16*)(wsb);          // 9216 f16 = 18432 B
    _Float16* wn1lo = (_Float16*)(wsb + 18432);
    _Float16* wn2hi = (_Float16*)(wsb + 36864);
    _Float16* wn2lo = (_Float16*)(wsb + 55296);
    float*    wn3   = (float*)(wsb + 73728);     // 1024 f32 = 4096 B
    float*    params= (float*)(wsb + 77824);     //  128 f32 =  512 B
    unsigned int* h1= (unsigned int*)(wsb + 78336);  // 32*65536*32 u32 = 268435456 B

    const size_t need = 78336 + (size_t)32*65536*32*4;
    if (ws_size < need) return;  // fail visibly rather than corrupt memory

    float* out = (float*)d_out;

    prep_kernel<<<1, 256, 0, stream>>>(w1,p1,q1, w2,p2,q2, w3,p3,q3,
                                       wn1hi, wn1lo, wn2hi, wn2lo, wn3, params);

    // merged: L1 (bx<128) + residual pool (bx>=128)
    scs3x3_l1_pool<<<dim3(144, 32), 512, 0, stream>>>(
        x, wn1hi, wn1lo, wn3, params, h1, out);

    // layer 2 + maxabs pool (reverse batch order): h1 -> out += pooled
    scs3x3_l2<<<dim3(128, 32), 512, 0, stream>>>(
        h1, wn2hi, wn2lo, params+32, params+97, out);
}